// Round 10
// baseline (517.747 us; speedup 1.0000x reference)
//
#include <hip/hip_runtime.h>

#define NFEAT 128
#define BT 2048        // edges per bucketing block
#define BSH 9          // log2(nodes per bucket)
#define BSZ 512        // nodes per bucket
#define NP 256         // bn partial blocks

typedef __attribute__((ext_vector_type(8))) short short8v;
typedef __attribute__((ext_vector_type(4))) float float4v;

static inline size_t align_up(size_t x, size_t a) { return (x + a - 1) & ~(a - 1); }

__device__ inline unsigned short f2bf(float f) {  // RNE float->bf16
  unsigned u = __float_as_uint(f);
  u += 0x7FFF + ((u >> 16) & 1);
  return (unsigned short)(u >> 16);
}
__device__ inline unsigned pack2bf(float lo, float hi) {
  return ((unsigned)f2bf(lo)) | (((unsigned)f2bf(hi)) << 16);
}
__device__ inline float bflo(unsigned u) { return __uint_as_float(u << 16); }
__device__ inline float bfhi(unsigned u) { return __uint_as_float(u & 0xFFFF0000u); }

// ---------------- K1: per-block bucket histograms, no global atomics ----
__global__ __launch_bounds__(256) void k_bcount(const int* __restrict__ src,
                                                const int* __restrict__ dst,
                                                int* __restrict__ cnt, int E, int nb, int NBK) {
  __shared__ int hD[256], hS[256];
  const int t = threadIdx.x, b = blockIdx.x;
  hD[t] = 0; hS[t] = 0;
  __syncthreads();
  const int e0 = b * BT, e1 = min(E, e0 + BT);
  for (int e = e0 + t; e < e1; e += 256) {
    atomicAdd(&hD[dst[e] >> BSH], 1);
    atomicAdd(&hS[src[e] >> BSH], 1);
  }
  __syncthreads();
  if (t < NBK) {
    cnt[t * nb + b] = hD[t];
    cnt[(NBK + t) * nb + b] = hS[t];
  }
}

// ---------------- exclusive scan over count matrix (3 phases) ----------------
__global__ __launch_bounds__(512) void k_scanA(const int* __restrict__ in,
                                               int* __restrict__ out,
                                               int* __restrict__ bsum, int n) {
  __shared__ int tmp[512];
  const int t = threadIdx.x;
  const int i = blockIdx.x * 512 + t;
  int v = (i < n) ? in[i] : 0;
  tmp[t] = v;
  __syncthreads();
  for (int off = 1; off < 512; off <<= 1) {
    int y = (t >= off) ? tmp[t - off] : 0;
    __syncthreads();
    tmp[t] += y;
    __syncthreads();
  }
  int incl = tmp[t];
  if (i < n) out[i] = incl - v;
  if (t == 511) bsum[blockIdx.x] = incl;
}

__global__ __launch_bounds__(1024) void k_scanB(const int* __restrict__ bsum,
                                                int* __restrict__ bscan, int nb1) {
  __shared__ int tmp[1024];
  const int t = threadIdx.x;
  int v = (t < nb1) ? bsum[t] : 0;
  tmp[t] = v;
  __syncthreads();
  for (int off = 1; off < 1024; off <<= 1) {
    int y = (t >= off) ? tmp[t - off] : 0;
    __syncthreads();
    tmp[t] += y;
    __syncthreads();
  }
  bscan[t] = tmp[t] - v;
}

__global__ __launch_bounds__(512) void k_scanC(int* __restrict__ out,
                                               const int* __restrict__ bscan, int n) {
  const int i = blockIdx.x * 512 + threadIdx.x;
  if (i < n) out[i] += bscan[blockIdx.x];
}

// ---------------- K2: place edges into bucketed arrays via LDS cursors ----------------
__global__ __launch_bounds__(256) void k_bplace(const int* __restrict__ src,
                                                const int* __restrict__ dst,
                                                const int* __restrict__ off,
                                                int* __restrict__ buf, int E, int nb, int NBK) {
  __shared__ int cD[256], cS[256];
  const int t = threadIdx.x, b = blockIdx.x;
  if (t < NBK) {
    cD[t] = off[t * nb + b];
    cS[t] = off[(NBK + t) * nb + b];
  }
  __syncthreads();
  const int e0 = b * BT, e1 = min(E, e0 + BT);
  for (int e = e0 + t; e < e1; e += 256) {
    int s = src[e];
    int d = dst[e];
    int pD = atomicAdd(&cD[d >> BSH], 1);          // LDS atomic
    buf[pD] = ((d & (BSZ - 1)) << 17) | s;
    int pS = atomicAdd(&cS[s >> BSH], 1);          // LDS atomic
    buf[pS] = s;
  }
}

// ---------------- K4: per-bucket CSR finish (row_ptr, rsq_in, col) ----------------
__global__ __launch_bounds__(256) void k_bcsr(const int* __restrict__ buf,
                                              const int* __restrict__ off,
                                              int* __restrict__ row_ptr,
                                              float* __restrict__ rsq_in,
                                              int* __restrict__ col,
                                              int E, int nb, int NBK, int N) {
  const int k = blockIdx.x, t = threadIdx.x;
  const int lo = off[k * nb];
  const int hi = (k + 1 < NBK) ? off[(k + 1) * nb] : E;
  __shared__ int cnt[BSZ];
  __shared__ int sc[BSZ];
  __shared__ int part[64];
  cnt[t] = 0; cnt[t + 256] = 0;
  __syncthreads();
  for (int e = lo + t; e < hi; e += 256) atomicAdd(&cnt[((unsigned)buf[e]) >> 17], 1);
  __syncthreads();
  if (t < 64) {
    int r = 0;
#pragma unroll
    for (int j = 0; j < 8; ++j) r += cnt[t * 8 + j];
    part[t] = r;
  }
  __syncthreads();
  if (t == 0) {
    int run = 0;
    for (int i = 0; i < 64; ++i) { int v = part[i]; part[i] = run; run += v; }
  }
  __syncthreads();
  if (t < 64) {
    int run = part[t];
#pragma unroll
    for (int j = 0; j < 8; ++j) { int v = cnt[t * 8 + j]; sc[t * 8 + j] = run; run += v; }
  }
  __syncthreads();
  for (int idx = t; idx < BSZ; idx += 256) {
    int n = (k << BSH) + idx;
    if (n < N) {
      row_ptr[n] = lo + sc[idx];
      int c = cnt[idx]; if (c < 1) c = 1;
      rsq_in[n] = 1.0f / sqrtf((float)c);
    }
    cnt[idx] = sc[idx];   // reset as cursor
  }
  if (k == NBK - 1 && t == 0) row_ptr[N] = E;
  __syncthreads();
  for (int e = lo + t; e < hi; e += 256) {
    int w = buf[e];
    int p = atomicAdd(&cnt[((unsigned)w) >> 17], 1);  // LDS atomic
    col[lo + p] = w & 0x1FFFF;
  }
}

// ---------------- K5: per-bucket src-degree -> rsq_out ----------------
__global__ __launch_bounds__(256) void k_bdeg(const int* __restrict__ buf,
                                              const int* __restrict__ off,
                                              float* __restrict__ rsq_out,
                                              int E, int nb, int NBK, int N) {
  const int k = blockIdx.x, t = threadIdx.x;
  const int lo = off[(NBK + k) * nb];
  const int hi = (k + 1 < NBK) ? off[(NBK + k + 1) * nb] : 2 * E;
  __shared__ int cnt[BSZ];
  cnt[t] = 0; cnt[t + 256] = 0;
  __syncthreads();
  for (int e = lo + t; e < hi; e += 256) atomicAdd(&cnt[buf[e] & (BSZ - 1)], 1);
  __syncthreads();
  for (int idx = t; idx < BSZ; idx += 256) {
    int n = (k << BSH) + idx;
    if (n < N) {
      int c = cnt[idx]; if (c < 1) c = 1;
      rsq_out[n] = 1.0f / sqrtf((float)c);
    }
  }
}

// ---------------- W prep: transpose + bf16 convert ----------------
__global__ __launch_bounds__(256) void k_wprep(const float* __restrict__ W0,
                                               const float* __restrict__ W1,
                                               const float* __restrict__ W2,
                                               unsigned short* __restrict__ Wt0,
                                               unsigned short* __restrict__ Wt1,
                                               unsigned short* __restrict__ Wt2) {
  int t = blockIdx.x * 256 + threadIdx.x;
  if (t < 16384) {
    int c = t >> 7, k = t & 127;
    Wt0[c * 128 + k] = f2bf(W0[k * 128 + c]);
  } else if (t < 32768) {
    int u = t - 16384;
    int c = u >> 7, k = u & 127;
    Wt1[c * 128 + k] = f2bf(W1[k * 128 + c]);
  } else if (t < 40960) {
    int u = t - 32768;
    int c = u >> 7, k = u & 127;
    Wt2[c * 128 + k] = f2bf(W2[k * 64 + c]);
  }
}

// ---------------- MFMA GEMM ----------------
// mode 0: X32 fp32 input, no transform. mode 1: Xbf bf16 input, BN scale/shift + relu.
// 64 rows/block, CC cols, K=128. LDS XOR swizzle byte^=((row&7)<<4).
template <int CC>
__global__ __launch_bounds__(256) void k_gemm_mfma(
    const float* __restrict__ X32, const unsigned short* __restrict__ Xbf,
    const unsigned short* __restrict__ Wt,
    unsigned short* __restrict__ Ybf, const float* __restrict__ rsq_out,
    const float* __restrict__ bnscale, const float* __restrict__ bnshift,
    int Nrows, int mode) {
  constexpr int XBYTES = 64 * 256;          // 16 KB
  constexpr int WBYTES = CC * 256;          // 32 or 16 KB
  __shared__ __align__(16) char lds[XBYTES + WBYTES];
  const int tid = threadIdx.x;
  const int rowBase = blockIdx.x * 64;

  // ---- stage W tile ----
  for (int u = tid; u < CC * 16; u += 256) {
    int c = u >> 4, kq = u & 15;
    uint4 v = *(const uint4*)(Wt + c * 128 + kq * 8);
    int byte = (c * 256 + kq * 16) ^ ((c & 7) << 4);
    *(uint4*)(&lds[XBYTES + byte]) = v;
  }
  // ---- stage X tile ----
  if (mode == 0) {
#pragma unroll
    for (int i = 0; i < 8; ++i) {
      int u = tid + i * 256;                // 2048 float4-units
      int r = u >> 5, kq = u & 31;
      int gr = rowBase + r;
      float4 v = make_float4(0.f, 0.f, 0.f, 0.f);
      if (gr < Nrows) v = *(const float4*)(X32 + (size_t)gr * 128 + kq * 4);
      ushort4 o;
      o.x = f2bf(v.x); o.y = f2bf(v.y); o.z = f2bf(v.z); o.w = f2bf(v.w);
      int byte = (r * 256 + kq * 8) ^ ((r & 7) << 4);
      *(ushort4*)(&lds[byte]) = o;
    }
  } else {
#pragma unroll
    for (int i = 0; i < 4; ++i) {
      int u = tid + i * 256;                // 1024 uint4-units (8 bf16 each)
      int r = u >> 4, kq = u & 15;
      int gr = rowBase + r;
      uint4 v = make_uint4(0, 0, 0, 0);
      if (gr < Nrows) v = *(const uint4*)(Xbf + (size_t)gr * 128 + kq * 8);
      float f0 = bflo(v.x), f1 = bfhi(v.x), f2 = bflo(v.y), f3 = bfhi(v.y);
      float f4 = bflo(v.z), f5 = bfhi(v.z), f6 = bflo(v.w), f7 = bfhi(v.w);
      const float4 sA = *(const float4*)(bnscale + kq * 8);
      const float4 sB = *(const float4*)(bnscale + kq * 8 + 4);
      const float4 hA = *(const float4*)(bnshift + kq * 8);
      const float4 hB = *(const float4*)(bnshift + kq * 8 + 4);
      f0 = fmaxf(f0 * sA.x + hA.x, 0.f); f1 = fmaxf(f1 * sA.y + hA.y, 0.f);
      f2 = fmaxf(f2 * sA.z + hA.z, 0.f); f3 = fmaxf(f3 * sA.w + hA.w, 0.f);
      f4 = fmaxf(f4 * sB.x + hB.x, 0.f); f5 = fmaxf(f5 * sB.y + hB.y, 0.f);
      f6 = fmaxf(f6 * sB.z + hB.z, 0.f); f7 = fmaxf(f7 * sB.w + hB.w, 0.f);
      uint4 o;
      o.x = pack2bf(f0, f1); o.y = pack2bf(f2, f3);
      o.z = pack2bf(f4, f5); o.w = pack2bf(f6, f7);
      int byte = (r * 256 + kq * 16) ^ ((r & 7) << 4);
      *(uint4*)(&lds[byte]) = o;
    }
  }
  __syncthreads();

  const int wv = tid >> 6;
  const int l = tid & 63;
  const int l16 = l & 15, lk = l >> 4;

  short8v a[4];
  const int arow = wv * 16 + l16;
#pragma unroll
  for (int kk = 0; kk < 4; ++kk) {
    int byte = (arow * 256 + kk * 64 + lk * 16) ^ ((arow & 7) << 4);
    a[kk] = *(const short8v*)(&lds[byte]);
  }

  float4v acc[CC / 16];
#pragma unroll
  for (int ct = 0; ct < CC / 16; ++ct) acc[ct] = (float4v){0.f, 0.f, 0.f, 0.f};

#pragma unroll
  for (int ct = 0; ct < CC / 16; ++ct) {
    const int col = ct * 16 + l16;
#pragma unroll
    for (int kk = 0; kk < 4; ++kk) {
      int byte = XBYTES + ((col * 256 + kk * 64 + lk * 16) ^ ((col & 7) << 4));
      short8v b = *(const short8v*)(&lds[byte]);
      acc[ct] = __builtin_amdgcn_mfma_f32_16x16x32_bf16(a[kk], b, acc[ct], 0, 0, 0);
    }
  }

  const int row0 = rowBase + wv * 16 + lk * 4;
  float scr[4];
#pragma unroll
  for (int r = 0; r < 4; ++r) scr[r] = (row0 + r < Nrows) ? rsq_out[row0 + r] : 0.f;
#pragma unroll
  for (int ct = 0; ct < CC / 16; ++ct) {
#pragma unroll
    for (int r = 0; r < 4; ++r) {
      int row = row0 + r;
      if (row < Nrows)
        Ybf[(size_t)row * CC + ct * 16 + l16] = f2bf(acc[ct][r] * scr[r]);
    }
  }
}

// ---------------- SpMM v2: one node per WAVE, edge-group parallel ----------------
// F=128: 16 feature-lanes x 4 edge-groups. F=64: 8 x 8. fp32 accumulate.
// OUT_BF=1 -> write bf16 h; OUT_BF=0 -> write fp32 (final output).
template <int F, int OUT_BF>
__global__ __launch_bounds__(256) void k_spmm2(const int* __restrict__ row_ptr,
                                               const int* __restrict__ colidx,
                                               const unsigned short* __restrict__ xW,
                                               void* __restrict__ outv,
                                               const float* __restrict__ rsq_in,
                                               const float* __restrict__ bias, int Nrows) {
  constexpr int FL = F / 8;   // feature lanes
  constexpr int G = 64 / FL;  // edge groups per wave
  const int node = blockIdx.x * 4 + (threadIdx.x >> 6);
  if (node >= Nrows) return;
  const int l = threadIdx.x & 63;
  const int fl = l % FL, g = l / FL;
  const int e0 = row_ptr[node];
  const int e1 = row_ptr[node + 1];
  float acc[8] = {};
  int e = e0 + g;
  for (; e + G < e1; e += 2 * G) {
    int s0 = colidx[e];
    int s1 = colidx[e + G];
    uint4 v0 = *(const uint4*)&xW[(size_t)s0 * F + fl * 8];
    uint4 v1 = *(const uint4*)&xW[(size_t)s1 * F + fl * 8];
    acc[0] += bflo(v0.x); acc[1] += bfhi(v0.x); acc[2] += bflo(v0.y); acc[3] += bfhi(v0.y);
    acc[4] += bflo(v0.z); acc[5] += bfhi(v0.z); acc[6] += bflo(v0.w); acc[7] += bfhi(v0.w);
    acc[0] += bflo(v1.x); acc[1] += bfhi(v1.x); acc[2] += bflo(v1.y); acc[3] += bfhi(v1.y);
    acc[4] += bflo(v1.z); acc[5] += bfhi(v1.z); acc[6] += bflo(v1.w); acc[7] += bfhi(v1.w);
  }
  if (e < e1) {
    int s0 = colidx[e];
    uint4 v0 = *(const uint4*)&xW[(size_t)s0 * F + fl * 8];
    acc[0] += bflo(v0.x); acc[1] += bfhi(v0.x); acc[2] += bflo(v0.y); acc[3] += bfhi(v0.y);
    acc[4] += bflo(v0.z); acc[5] += bfhi(v0.z); acc[6] += bflo(v0.w); acc[7] += bfhi(v0.w);
  }
  // cross-group reduce (groups strided by FL lanes)
#pragma unroll
  for (int m = FL; m < 64; m <<= 1) {
#pragma unroll
    for (int j = 0; j < 8; ++j) acc[j] += __shfl_xor(acc[j], m);
  }
  if (g != 0) return;
  const float sc = rsq_in[node];
  const float4 bA = *(const float4*)&bias[fl * 8];
  const float4 bB = *(const float4*)&bias[fl * 8 + 4];
  float o0 = acc[0] * sc + bA.x, o1 = acc[1] * sc + bA.y;
  float o2 = acc[2] * sc + bA.z, o3 = acc[3] * sc + bA.w;
  float o4 = acc[4] * sc + bB.x, o5 = acc[5] * sc + bB.y;
  float o6 = acc[6] * sc + bB.z, o7 = acc[7] * sc + bB.w;
  if (OUT_BF) {
    uint4 w;
    w.x = pack2bf(o0, o1); w.y = pack2bf(o2, o3);
    w.z = pack2bf(o4, o5); w.w = pack2bf(o6, o7);
    *(uint4*)&((unsigned short*)outv)[(size_t)node * F + fl * 8] = w;
  } else {
    float* out = (float*)outv;
    *(float4*)&out[(size_t)node * F + fl * 8] = make_float4(o0, o1, o2, o3);
    *(float4*)&out[(size_t)node * F + fl * 8 + 4] = make_float4(o4, o5, o6, o7);
  }
}

// ---------------- BN stats over bf16 h -> per-block partials (no atomics) ----------------
__global__ __launch_bounds__(256) void k_bn_stats_bf(const unsigned short* __restrict__ h,
                                                     float* __restrict__ psum,
                                                     float* __restrict__ pssq, int Nrows) {
  const int t = threadIdx.x;
  const int fs = t & 15;          // feature slot: 8 feats
  const int rg = t >> 4;          // row group 0..15
  float s[8] = {}, ss[8] = {};
  for (int r = blockIdx.x * 16 + rg; r < Nrows; r += gridDim.x * 16) {
    uint4 v = *(const uint4*)&h[(size_t)r * 128 + fs * 8];
    float f0 = bflo(v.x), f1 = bfhi(v.x), f2 = bflo(v.y), f3 = bfhi(v.y);
    float f4 = bflo(v.z), f5 = bfhi(v.z), f6 = bflo(v.w), f7 = bfhi(v.w);
    s[0] += f0; ss[0] += f0 * f0; s[1] += f1; ss[1] += f1 * f1;
    s[2] += f2; ss[2] += f2 * f2; s[3] += f3; ss[3] += f3 * f3;
    s[4] += f4; ss[4] += f4 * f4; s[5] += f5; ss[5] += f5 * f5;
    s[6] += f6; ss[6] += f6 * f6; s[7] += f7; ss[7] += f7 * f7;
  }
#pragma unroll
  for (int m = 16; m < 64; m <<= 1) {
#pragma unroll
    for (int j = 0; j < 8; ++j) { s[j] += __shfl_xor(s[j], m); ss[j] += __shfl_xor(ss[j], m); }
  }
  __shared__ float lsum[4][128], lssq[4][128];
  const int wv = t >> 6, wl = t & 63;
  if (wl < 16) {
#pragma unroll
    for (int j = 0; j < 8; ++j) { lsum[wv][wl * 8 + j] = s[j]; lssq[wv][wl * 8 + j] = ss[j]; }
  }
  __syncthreads();
  if (t < 128) {
    psum[(size_t)blockIdx.x * 128 + t] = lsum[0][t] + lsum[1][t] + lsum[2][t] + lsum[3][t];
    pssq[(size_t)blockIdx.x * 128 + t] = lssq[0][t] + lssq[1][t] + lssq[2][t] + lssq[3][t];
  }
}

__global__ __launch_bounds__(256) void k_bn_final(const float* __restrict__ psum,
                                                  const float* __restrict__ pssq,
                                                  const float* __restrict__ gamma,
                                                  const float* __restrict__ beta,
                                                  float* __restrict__ scale,
                                                  float* __restrict__ shift, int Nrows) {
  const int t = threadIdx.x;
  const int f = t & 127, half = t >> 7;
  float s = 0.f, ss = 0.f;
  for (int b = half * (NP / 2); b < (half + 1) * (NP / 2); ++b) {
    s += psum[(size_t)b * 128 + f];
    ss += pssq[(size_t)b * 128 + f];
  }
  __shared__ float ls[2][128], lss[2][128];
  ls[half][f] = s; lss[half][f] = ss;
  __syncthreads();
  if (t < 128) {
    float sum = ls[0][t] + ls[1][t];
    float sumsq = lss[0][t] + lss[1][t];
    float inv_n = 1.0f / (float)Nrows;
    float mean = sum * inv_n;
    float var = sumsq * inv_n - mean * mean;
    if (var < 0.f) var = 0.f;
    float sc = gamma[t] * (1.0f / sqrtf(var + 1e-5f));
    scale[t] = sc;
    shift[t] = beta[t] - mean * sc;
  }
}

extern "C" void kernel_launch(void* const* d_in, const int* in_sizes, int n_in,
                              void* d_out, int out_size, void* d_ws, size_t ws_size,
                              hipStream_t stream) {
  const float* in_feat = (const float*)d_in[0];
  const int* src = (const int*)d_in[1];
  const int* dst = (const int*)d_in[2];
  const float* W0 = (const float*)d_in[3];
  const float* b0 = (const float*)d_in[4];
  const float* W1 = (const float*)d_in[5];
  const float* b1 = (const float*)d_in[6];
  const float* W2 = (const float*)d_in[7];
  const float* b2 = (const float*)d_in[8];
  const float* gamma0 = (const float*)d_in[9];
  const float* beta0 = (const float*)d_in[10];
  const float* gamma1 = (const float*)d_in[11];
  const float* beta1 = (const float*)d_in[12];
  float* out = (float*)d_out;

  const int N = in_sizes[0] / NFEAT;
  const int E = in_sizes[1];

  const int nb = (E + BT - 1) / BT;
  const int NBK = (N + BSZ - 1) / BSZ;
  const int L = 2 * NBK * nb;
  const int nb1 = (L + 511) / 512;

  // ---- carve workspace ----
  char* p = (char*)d_ws;
  auto carve = [&](size_t bytes) {
    char* q = p;
    p += align_up(bytes, 256);
    return q;
  };
  int* cnt = (int*)carve((size_t)L * 4);
  int* off = (int*)carve((size_t)L * 4);
  int* bsum = (int*)carve(1024 * 4);
  int* bscan = (int*)carve(1024 * 4);
  int* row_ptr = (int*)carve((size_t)(N + 1) * 4);
  int* col = (int*)carve((size_t)E * 4);
  float* rsq_out = (float*)carve((size_t)N * 4);
  float* rsq_in = (float*)carve((size_t)N * 4);
  float* psum0 = (float*)carve((size_t)NP * 128 * 4);
  float* pssq0 = (float*)carve((size_t)NP * 128 * 4);
  float* psum1 = (float*)carve((size_t)NP * 128 * 4);
  float* pssq1 = (float*)carve((size_t)NP * 128 * 4);
  float* bn_scale0 = (float*)carve(128 * 4);
  float* bn_shift0 = (float*)carve(128 * 4);
  float* bn_scale1 = (float*)carve(128 * 4);
  float* bn_shift1 = (float*)carve(128 * 4);
  unsigned short* Wt0 = (unsigned short*)carve(16384 * 2);
  unsigned short* Wt1 = (unsigned short*)carve(16384 * 2);
  unsigned short* Wt2 = (unsigned short*)carve(8192 * 2);
  unsigned short* xWbf = (unsigned short*)carve((size_t)N * NFEAT * 2);  // bf16 GEMM out
  unsigned short* hbf = (unsigned short*)carve((size_t)N * NFEAT * 2);   // bf16 h
  int* buf = (int*)carve((size_t)2 * E * 4);                             // bucketed edges

  // ---- W prep + atomic-free CSR + degree pipeline ----
  k_wprep<<<160, 256, 0, stream>>>(W0, W1, W2, Wt0, Wt1, Wt2);
  k_bcount<<<nb, 256, 0, stream>>>(src, dst, cnt, E, nb, NBK);
  k_scanA<<<nb1, 512, 0, stream>>>(cnt, off, bsum, L);
  k_scanB<<<1, 1024, 0, stream>>>(bsum, bscan, nb1);
  k_scanC<<<nb1, 512, 0, stream>>>(off, bscan, L);
  k_bplace<<<nb, 256, 0, stream>>>(src, dst, off, buf, E, nb, NBK);
  k_bcsr<<<NBK, 256, 0, stream>>>(buf, off, row_ptr, rsq_in, col, E, nb, NBK, N);
  k_bdeg<<<NBK, 256, 0, stream>>>(buf, off, rsq_out, E, nb, NBK, N);

  const int GR = (N + 63) / 64;
  const int GS = (N + 3) / 4;  // spmm2: 4 nodes (waves) per block

  // ---- layer 0 ----
  k_gemm_mfma<128><<<GR, 256, 0, stream>>>(in_feat, nullptr, Wt0, xWbf, rsq_out,
                                           nullptr, nullptr, N, 0);
  k_spmm2<128, 1><<<GS, 256, 0, stream>>>(row_ptr, col, xWbf, hbf, rsq_in, b0, N);
  k_bn_stats_bf<<<NP, 256, 0, stream>>>(hbf, psum0, pssq0, N);
  k_bn_final<<<1, 256, 0, stream>>>(psum0, pssq0, gamma0, beta0, bn_scale0, bn_shift0, N);

  // ---- layer 1 ----
  k_gemm_mfma<128><<<GR, 256, 0, stream>>>(nullptr, hbf, Wt1, xWbf, rsq_out,
                                           bn_scale0, bn_shift0, N, 1);
  k_spmm2<128, 1><<<GS, 256, 0, stream>>>(row_ptr, col, xWbf, hbf, rsq_in, b1, N);
  k_bn_stats_bf<<<NP, 256, 0, stream>>>(hbf, psum1, pssq1, N);
  k_bn_final<<<1, 256, 0, stream>>>(psum1, pssq1, gamma1, beta1, bn_scale1, bn_shift1, N);

  // ---- layer 2 (output 64 classes, fp32) ----
  k_gemm_mfma<64><<<GR, 256, 0, stream>>>(nullptr, hbf, Wt2, xWbf, rsq_out,
                                          bn_scale1, bn_shift1, N, 1);
  k_spmm2<64, 0><<<GS, 256, 0, stream>>>(row_ptr, col, xWbf, out, rsq_in, b2, N);
}